// Round 16
// baseline (27.314 us; speedup 1.0000x reference)
//
#include <hip/hip_runtime.h>
#include <hip/hip_bf16.h>

#define N_ATOMS 51200

// Output layout (flat floats, reference return order):
//   energy[512]@0, forces[153600]@512, stress[4608]@154112,
//   energy_uncert[512]@158720 (=0.6), force_uncert[153600]@159232 (computed),
//   stress_uncert[4608]@312832 (=0.1/16)
#define OUT_FUNC 159232

typedef __attribute__((ext_vector_type(4))) float f32x4;
typedef __attribute__((ext_vector_type(2))) unsigned u32x2;
typedef __attribute__((ext_vector_type(4))) unsigned u32x4;
typedef __attribute__((ext_vector_type(8))) short s16x8;

constexpr int BLK = 256;

__device__ __forceinline__ unsigned pack2(float lo, float hi) {
    return __builtin_amdgcn_perm(__float_as_uint(hi), __float_as_uint(lo), 0x07060302);
}
__device__ __forceinline__ s16x8 pack8(f32x4 lo, f32x4 hi) {
    union { u32x4 u; s16x8 s; } c;
    c.u.x = pack2(lo.x, lo.y); c.u.y = pack2(lo.z, lo.w);
    c.u.z = pack2(hi.x, hi.y); c.u.w = pack2(hi.z, hi.w);
    return c.s;
}
__device__ __forceinline__ short bftrunc(float x) {
    return (short)(__float_as_uint(x) >> 16);
}
__device__ __forceinline__ float silu_(float v) { return v / (1.0f + __expf(-v)); }

// Raw barrier discipline: NO vmcnt drain in the loop (that's what __syncthreads
// does and what flattened every previous prefetch). Only lgkm + barrier.
#define LGKM0()   asm volatile("s_waitcnt lgkmcnt(0)" ::: "memory")
#define RAWBAR()  asm volatile("s_barrier" ::: "memory")

__global__ __launch_bounds__(BLK, 5) void funcert_kernel(
    const float* __restrict__ nf,
    const float* __restrict__ energy,
    const float* __restrict__ forces,
    const float* __restrict__ stress,
    const float* __restrict__ W1f, const float* __restrict__ b1f,
    const float* __restrict__ W2f, const float* __restrict__ b2f,
    const float* __restrict__ W3f, const float* __restrict__ b3f,
    float* __restrict__ out)
{
    const int t   = threadIdx.x;
    const int gid = blockIdx.x * BLK + t;

    __shared__ short Xq0[64 * 64];     // 8 KB bf16 quarter tile (ping)
    __shared__ short Xq1[64 * 64];     // 8 KB bf16 quarter tile (pong)
    __shared__ short H1s[64 * 64];     // 8 KB  -> total 24 KB = 5 blocks/CU OK

    const int lane  = t & 63;
    const int w     = t >> 6;
    const int g     = lane >> 4;
    const int col   = lane & 15;
    const int abase = blockIdx.x * 64;
    const int ch    = w * 16 + col;

    const int rb  = t >> 4;            // staging row base (0..15), rows rb+16i
    const int f4c = t & 15;            // f4 column within quarter
    const float4* nfr = (const float4*)nf + (size_t)(abase + rb) * 96 + f4c;
    const int wbyte0 = rb * 128 + (f4c & 1) * 8;

    #define XQ_ISSUE(dst, qb)                                            \
        { _Pragma("unroll")                                              \
          for (int i = 0; i < 4; ++i)                                    \
              dst[i] = *(const f32x4*)(nfr + (size_t)i * 16 * 96 + (qb)); }

    #define XQ_STASH(buf, src)                                           \
        { _Pragma("unroll")                                              \
          for (int i = 0; i < 4; ++i) {                                  \
              const int r = rb + 16 * i;                                 \
              u32x2 bb;                                                  \
              bb.x = pack2(src[i].x, src[i].y);                          \
              bb.y = pack2(src[i].z, src[i].w);                          \
              *(u32x2*)((char*)(buf) + (wbyte0 + 2048 * i +              \
                        ((((f4c >> 1) ^ (r & 7))) << 4))) = bb;          \
          } }

    #define WQ_ISSUE(dst, q)                                             \
        { _Pragma("unroll")                                              \
          for (int ks2 = 0; ks2 < 2; ++ks2) {                            \
              const float* p = W1f + ch * 256 + (q) * 64 + ks2 * 32 + g * 8; \
              dst[2 * ks2]     = *(const f32x4*)p;                       \
              dst[2 * ks2 + 1] = *(const f32x4*)(p + 4);                 \
          } }

    #define Q_COMPUTE(buf, wfv)                                          \
        { _Pragma("unroll")                                              \
          for (int mt = 0; mt < 4; ++mt) {                               \
              const int row = mt * 16 + col;                             \
              _Pragma("unroll")                                          \
              for (int ks2 = 0; ks2 < 2; ++ks2) {                        \
                  const int sl = (ks2 * 4 + g) ^ (row & 7);              \
                  const s16x8 af = *(const s16x8*)((buf) + row * 64 + sl * 8); \
                  acc[mt] = __builtin_amdgcn_mfma_f32_16x16x32_bf16(af, wfv[ks2], acc[mt], 0, 0, 0); \
              } } }

    // ---- copy load first (oldest in queue; drains with the first pack) ----
    f32x4 cv = {0.f, 0.f, 0.f, 0.f}; int co = -1;
    if (gid < 40960) {
        co = gid;
        if      (gid < 128)   { cv = ((const f32x4*)energy)[gid]; }
        else if (gid < 38528) { cv = ((const f32x4*)forces)[gid - 128]; }
        else if (gid < 39680) { cv = ((const f32x4*)stress)[gid - 38528]; }
        else if (gid < 39808) { cv = (f32x4){0.6f, 0.6f, 0.6f, 0.6f}; }
        else { cv = (f32x4){0.00625f, 0.00625f, 0.00625f, 0.00625f}; co = gid + 38400; }
    }

    // ---- prologue: 2-deep — W0,X0,W1,X1 in flight ----
    f32x4 wv0[4], wv1[4], x0[4], x1[4];
    WQ_ISSUE(wv0, 0);
    XQ_ISSUE(x0, 0);
    WQ_ISSUE(wv1, 1);
    XQ_ISSUE(x1, 16);
    const float b1v = b1f[ch];

    f32x4 acc[4];
    #pragma unroll
    for (int mt = 0; mt < 4; ++mt) acc[mt] = (f32x4){0.f, 0.f, 0.f, 0.f};
    s16x8 wf[2];

    // ---- phase 0 (Q0 -> Xq0); issue Q2 into freed regs; NO vmcnt drain ----
    wf[0] = pack8(wv0[0], wv0[1]); wf[1] = pack8(wv0[2], wv0[3]);  // waits W0 (counted)
    XQ_STASH(Xq0, x0);                                             // waits X0 (counted)
    WQ_ISSUE(wv0, 2);
    XQ_ISSUE(x0, 64);                                              // concat jump
    LGKM0(); RAWBAR();                                             // Xq0 visible
    Q_COMPUTE(Xq0, wf);

    // ---- phase 1 (Q1 -> Xq1); issue Q3 ----
    wf[0] = pack8(wv1[0], wv1[1]); wf[1] = pack8(wv1[2], wv1[3]);
    XQ_STASH(Xq1, x1);
    WQ_ISSUE(wv1, 3);
    XQ_ISSUE(x1, 80);
    LGKM0(); RAWBAR();                                             // Xq1 visible; also certifies compute(Q0) done block-wide
    Q_COMPUTE(Xq1, wf);

    // ---- phase 2 (Q2 -> Xq0) ----
    wf[0] = pack8(wv0[0], wv0[1]); wf[1] = pack8(wv0[2], wv0[3]);
    XQ_STASH(Xq0, x0);
    LGKM0(); RAWBAR();
    Q_COMPUTE(Xq0, wf);

    // ---- phase 3 (Q3 -> Xq1) ----
    wf[0] = pack8(wv1[0], wv1[1]); wf[1] = pack8(wv1[2], wv1[3]);
    XQ_STASH(Xq1, x1);
    LGKM0(); RAWBAR();
    Q_COMPUTE(Xq1, wf);

    // ---- bias + silu -> h1 (verified layout) ----
    #pragma unroll
    for (int mt = 0; mt < 4; ++mt) {
        #pragma unroll
        for (int r = 0; r < 4; ++r) {
            const int atom = mt * 16 + g * 4 + r;
            H1s[atom * 64 + ch] = bftrunc(silu_(acc[mt][r] + b1v));
        }
    }
    __syncthreads();

    // ---- L2: wave w -> atoms [16w,16w+16), 2 k-steps over 64 ch ----
    s16x8 w2frag[2];
    #pragma unroll
    for (int ks = 0; ks < 2; ++ks) {
        const float* p = W2f + col * 64 + ks * 32 + g * 8;   // B2[k][n] = W2f[n][k]
        w2frag[ks] = pack8(*(const f32x4*)p, *(const f32x4*)(p + 4));
    }
    const int arow = w * 16 + col;
    f32x4 a2 = {0.f, 0.f, 0.f, 0.f};
    #pragma unroll
    for (int ks = 0; ks < 2; ++ks) {
        const s16x8 af = *(const s16x8*)(H1s + arow * 64 + ks * 32 + g * 8);
        a2 = __builtin_amdgcn_mfma_f32_16x16x32_bf16(af, w2frag[ks], a2, 0, 0, 0);
    }

    // ---- h2 + L3 + exp ----
    const float b2v = b2f[col];
    const float w3v = W3f[col];
    float y[4];
    #pragma unroll
    for (int r = 0; r < 4; ++r)
        y[r] = silu_(a2[r] + b2v) * w3v;
    #pragma unroll
    for (int m = 1; m < 16; m <<= 1) {
        #pragma unroll
        for (int r = 0; r < 4; ++r)
            y[r] += __shfl_xor(y[r], m, 64);   // reduce over 16 cols
    }
    const float b3v = b3f[0];
    float fu[4];
    #pragma unroll
    for (int r = 0; r < 4; ++r)
        fu[r] = __expf(y[r] + b3v) * 0.1f;

    if (col < 12) {                            // 4 atoms x 3 comps per 16-lane group
        const int a_ = col / 3, c = col - a_ * 3;
        const float v = (a_ == 0) ? fu[0] : (a_ == 1) ? fu[1] : (a_ == 2) ? fu[2] : fu[3];
        const int atom = w * 16 + g * 4 + a_;
        out[OUT_FUNC + 3 * (abase + atom) + c] = v;
    }

    // ---- deferred passthrough store (cv long retired; zero wait) ----
    if (co >= 0) ((f32x4*)out)[co] = cv;
}

extern "C" void kernel_launch(void* const* d_in, const int* in_sizes, int n_in,
                              void* d_out, int out_size, void* d_ws, size_t ws_size,
                              hipStream_t stream) {
    const float* nf     = (const float*)d_in[0];
    const float* energy = (const float*)d_in[1];
    const float* forces = (const float*)d_in[2];
    const float* stress = (const float*)d_in[3];
    const float* W1f    = (const float*)d_in[10];
    const float* b1f    = (const float*)d_in[11];
    const float* W2f    = (const float*)d_in[12];
    const float* b2f    = (const float*)d_in[13];
    const float* W3f    = (const float*)d_in[14];
    const float* b3f    = (const float*)d_in[15];
    float* out = (float*)d_out;

    dim3 grid(N_ATOMS / 64);   // 800 blocks
    funcert_kernel<<<grid, BLK, 0, stream>>>(nf, energy, forces, stress,
                                             W1f, b1f, W2f, b2f, W3f, b3f, out);
}

// Round 17
// 19.896 us; speedup vs baseline: 1.3728x; 1.3728x over previous
//
#include <hip/hip_runtime.h>
#include <hip/hip_bf16.h>

#define N_ATOMS 51200

// Output layout (flat floats, reference return order):
//   energy[512]@0, forces[153600]@512, stress[4608]@154112,
//   energy_uncert[512]@158720 (=0.6), force_uncert[153600]@159232 (computed),
//   stress_uncert[4608]@312832 (=0.1/16)
#define OUT_FUNC 159232

typedef __attribute__((ext_vector_type(4))) float f32x4;
typedef __attribute__((ext_vector_type(4))) unsigned u32x4;
typedef __attribute__((ext_vector_type(8))) short s16x8;

constexpr int BLK = 256;

__device__ __forceinline__ unsigned pack2(float lo, float hi) {
    return __builtin_amdgcn_perm(__float_as_uint(hi), __float_as_uint(lo), 0x07060302);
}
__device__ __forceinline__ s16x8 pack8(f32x4 lo, f32x4 hi) {
    union { u32x4 u; s16x8 s; } c;
    c.u.x = pack2(lo.x, lo.y); c.u.y = pack2(lo.z, lo.w);
    c.u.z = pack2(hi.x, hi.y); c.u.w = pack2(hi.z, hi.w);
    return c.s;
}
__device__ __forceinline__ short bftrunc(float x) {
    return (short)(__float_as_uint(x) >> 16);
}
__device__ __forceinline__ float silu_(float v) { return v / (1.0f + __expf(-v)); }

#define VMCNT4()  asm volatile("s_waitcnt vmcnt(4)" ::: "memory")
#define VMCNT0()  asm volatile("s_waitcnt vmcnt(0)" ::: "memory")
#define RAWBAR()  asm volatile("s_barrier" ::: "memory")

__global__ __launch_bounds__(BLK, 5) void funcert_kernel(
    const float* __restrict__ nf,
    const float* __restrict__ energy,
    const float* __restrict__ forces,
    const float* __restrict__ stress,
    const float* __restrict__ W1f, const float* __restrict__ b1f,
    const float* __restrict__ W2f, const float* __restrict__ b2f,
    const float* __restrict__ W3f, const float* __restrict__ b3f,
    float* __restrict__ out)
{
    const int t   = threadIdx.x;
    const int gid = blockIdx.x * BLK + t;

    __shared__ float Xe[3][64 * 32];   // 3 x 8 KB f32 eighth-tiles (DMA dest)
    __shared__ short H1s[64 * 64];     // 8 KB -> total 32 KB = 5 blocks/CU

    const int lane  = t & 63;
    const int w     = t >> 6;
    const int g     = lane >> 4;
    const int col   = lane & 15;
    const int abase = blockIdx.x * 64;
    const int ch    = w * 16 + col;

    const int rloc = lane >> 3;        // row within an 8-row DMA group (= r&7)
    const int sl   = lane & 7;         // dest 16B slot within the 128B row

    // eighth e: logical floats [32e,32e+32); global offset adds +128 for e>=4 (concat)
    // 2 DMA instrs/wave/eighth, each 8 rows x 128B; LDS linear, source pre-swizzled
    #define GLD_E(buf, e)                                                    \
        { _Pragma("unroll")                                                  \
          for (int i = 0; i < 2; ++i) {                                      \
              const int br = w * 16 + i * 8;                                 \
              const float* src = nf + (size_t)(abase + br + rloc) * 384      \
                                 + (32 * (e) + ((e) >= 4 ? 128 : 0))         \
                                 + ((sl ^ rloc) << 2);                       \
              __builtin_amdgcn_global_load_lds(                              \
                  (const __attribute__((address_space(1))) void*)src,        \
                  (__attribute__((address_space(3))) void*)((buf) + br * 32),\
                  16, 0, 0);                                                 \
          } }

    #define WQ_E(dst, e)                                                     \
        { const float* p = W1f + ch * 256 + (e) * 32 + g * 8;                \
          dst[0] = *(const f32x4*)p;                                         \
          dst[1] = *(const f32x4*)(p + 4); }

    #define COMP_E(buf, wvv)                                                 \
        { const s16x8 wf = pack8(wvv[0], wvv[1]);                            \
          _Pragma("unroll")                                                  \
          for (int mt = 0; mt < 4; ++mt) {                                   \
              const int row = mt * 16 + col;                                 \
              const int s0  = (2 * g) ^ (row & 7);                           \
              const f32x4 lo = *(const f32x4*)((buf) + row * 32 + (s0)      * 4); \
              const f32x4 hi = *(const f32x4*)((buf) + row * 32 + (s0 ^ 1)  * 4); \
              acc[mt] = __builtin_amdgcn_mfma_f32_16x16x32_bf16(             \
                          pack8(lo, hi), wf, acc[mt], 0, 0, 0);              \
          } }

    // ---- copy load first; store deferred to end ----
    f32x4 cv = {0.f, 0.f, 0.f, 0.f}; int co = -1;
    if (gid < 40960) {
        co = gid;
        if      (gid < 128)   { cv = ((const f32x4*)energy)[gid]; }
        else if (gid < 38528) { cv = ((const f32x4*)forces)[gid - 128]; }
        else if (gid < 39680) { cv = ((const f32x4*)stress)[gid - 38528]; }
        else if (gid < 39808) { cv = (f32x4){0.6f, 0.6f, 0.6f, 0.6f}; }
        else { cv = (f32x4){0.00625f, 0.00625f, 0.00625f, 0.00625f}; co = gid + 38400; }
    }

    // ---- prologue: b1, then {D0,W0},{D1,W1} in flight ----
    const float b1v = b1f[ch];
    f32x4 wvA[2], wvB[2], wvC[2];
    GLD_E(Xe[0], 0);  WQ_E(wvA, 0);
    GLD_E(Xe[1], 1);  WQ_E(wvB, 1);

    f32x4 acc[4];
    #pragma unroll
    for (int mt = 0; mt < 4; ++mt) acc[mt] = (f32x4){0.f, 0.f, 0.f, 0.f};

    // ---- 8 phases: vmcnt(4) -> barrier -> issue e+2 -> pack+4 MFMA ----
    VMCNT4(); RAWBAR();  GLD_E(Xe[2], 2); WQ_E(wvC, 2);  COMP_E(Xe[0], wvA);  // e0
    VMCNT4(); RAWBAR();  GLD_E(Xe[0], 3); WQ_E(wvA, 3);  COMP_E(Xe[1], wvB);  // e1
    VMCNT4(); RAWBAR();  GLD_E(Xe[1], 4); WQ_E(wvB, 4);  COMP_E(Xe[2], wvC);  // e2
    VMCNT4(); RAWBAR();  GLD_E(Xe[2], 5); WQ_E(wvC, 5);  COMP_E(Xe[0], wvA);  // e3
    VMCNT4(); RAWBAR();  GLD_E(Xe[0], 6); WQ_E(wvA, 6);  COMP_E(Xe[1], wvB);  // e4
    VMCNT4(); RAWBAR();  GLD_E(Xe[1], 7); WQ_E(wvB, 7);  COMP_E(Xe[2], wvC);  // e5
    VMCNT4(); RAWBAR();                                  COMP_E(Xe[0], wvA);  // e6
    VMCNT0(); RAWBAR();                                  COMP_E(Xe[1], wvB);  // e7

    // ---- bias + silu -> h1 (verified layout) ----
    #pragma unroll
    for (int mt = 0; mt < 4; ++mt) {
        #pragma unroll
        for (int r = 0; r < 4; ++r) {
            const int atom = mt * 16 + g * 4 + r;
            H1s[atom * 64 + ch] = bftrunc(silu_(acc[mt][r] + b1v));
        }
    }
    __syncthreads();

    // ---- L2: wave w -> atoms [16w,16w+16), 2 k-steps over 64 ch ----
    s16x8 w2frag[2];
    #pragma unroll
    for (int ks = 0; ks < 2; ++ks) {
        const float* p = W2f + col * 64 + ks * 32 + g * 8;   // B2[k][n] = W2f[n][k]
        w2frag[ks] = pack8(*(const f32x4*)p, *(const f32x4*)(p + 4));
    }
    const int arow = w * 16 + col;
    f32x4 a2 = {0.f, 0.f, 0.f, 0.f};
    #pragma unroll
    for (int ks = 0; ks < 2; ++ks) {
        const s16x8 af = *(const s16x8*)(H1s + arow * 64 + ks * 32 + g * 8);
        a2 = __builtin_amdgcn_mfma_f32_16x16x32_bf16(af, w2frag[ks], a2, 0, 0, 0);
    }

    // ---- h2 + L3 + exp ----
    const float b2v = b2f[col];
    const float w3v = W3f[col];
    float y[4];
    #pragma unroll
    for (int r = 0; r < 4; ++r)
        y[r] = silu_(a2[r] + b2v) * w3v;
    #pragma unroll
    for (int m = 1; m < 16; m <<= 1) {
        #pragma unroll
        for (int r = 0; r < 4; ++r)
            y[r] += __shfl_xor(y[r], m, 64);   // reduce over 16 cols
    }
    const float b3v = b3f[0];
    float fu[4];
    #pragma unroll
    for (int r = 0; r < 4; ++r)
        fu[r] = __expf(y[r] + b3v) * 0.1f;

    if (col < 12) {                            // 4 atoms x 3 comps per 16-lane group
        const int a_ = col / 3, c = col - a_ * 3;
        const float v = (a_ == 0) ? fu[0] : (a_ == 1) ? fu[1] : (a_ == 2) ? fu[2] : fu[3];
        const int atom = w * 16 + g * 4 + a_;
        out[OUT_FUNC + 3 * (abase + atom) + c] = v;
    }

    // ---- deferred passthrough store ----
    if (co >= 0) ((f32x4*)out)[co] = cv;
}

extern "C" void kernel_launch(void* const* d_in, const int* in_sizes, int n_in,
                              void* d_out, int out_size, void* d_ws, size_t ws_size,
                              hipStream_t stream) {
    const float* nf     = (const float*)d_in[0];
    const float* energy = (const float*)d_in[1];
    const float* forces = (const float*)d_in[2];
    const float* stress = (const float*)d_in[3];
    const float* W1f    = (const float*)d_in[10];
    const float* b1f    = (const float*)d_in[11];
    const float* W2f    = (const float*)d_in[12];
    const float* b2f    = (const float*)d_in[13];
    const float* W3f    = (const float*)d_in[14];
    const float* b3f    = (const float*)d_in[15];
    float* out = (float*)d_out;

    dim3 grid(N_ATOMS / 64);   // 800 blocks
    funcert_kernel<<<grid, BLK, 0, stream>>>(nf, energy, forces, stress,
                                             W1f, b1f, W2f, b2f, W3f, b3f, out);
}